// Round 10
// baseline (83.822 us; speedup 1.0000x reference)
//
#include <hip/hip_runtime.h>

// RegionalCosineSimilarityLoss — B=8, T=2048, C=128; mapping sorted per batch, [0,64).
// R10: DIAGNOSTIC ROUND. Identical structure/arithmetic to R9, but each kernel
// repeats its body REPS=16x (idempotent, compiler-barrier'd) so per-kernel
// durations+counters become visible above the harness's 40us poison fills.
// dur/16 = warm marginal cost per kernel. Revert REPS in next round.

#define TT 2048
#define CC 128
#define TM 64
#define SLOTS 4
#define NTILES 256
#define TOTAL_BLK (NTILES * SLOTS)   // 1024
#define NORM_BLKS 4096               // 16384 rows / 4 rows-per-block
#define TBL_BLKS 64                  // 16384 rows / 256 boundary-threads-per-block
#define REPS 16

typedef unsigned short ushort_t;
typedef __attribute__((ext_vector_type(8))) short v8s;   // 8 bf16 (4 VGPRs)
typedef __attribute__((ext_vector_type(4))) float v4f;   // MFMA accumulator

__device__ __forceinline__ ushort_t f2bf(float f) {      // RNE f32->bf16 (finite data)
    unsigned u = __float_as_uint(f);
    return (ushort_t)((u + 0x7FFFu + ((u >> 16) & 1u)) >> 16);
}

// ---------------- Kernel 1: normalize->bf16  +  last_tbl boundary scatter ----------------
__global__ void __launch_bounds__(256) k_prep(const float* __restrict__ x,
                                              const int* __restrict__ map,
                                              ushort_t* __restrict__ xnb,
                                              int* __restrict__ last_tbl) {
    const int bid = blockIdx.x;
    const int tid = threadIdx.x;

    if (bid < NORM_BLKS) {
        const int wave = tid >> 6, lane = tid & 63;
        const int row  = bid * 4 + wave;
        for (int rep = 0; rep < REPS; ++rep) {
            asm volatile("" ::: "memory");   // force real re-execution each rep
            float2 v = ((const float2*)(x + (size_t)row * CC))[lane];
            float ss = v.x * v.x + v.y * v.y;
            #pragma unroll
            for (int off = 32; off; off >>= 1) ss += __shfl_xor(ss, off);
            const float rn = 1.0f / fmaxf(sqrtf(ss), 1e-8f);
            const unsigned lo = f2bf(v.x * rn), hi = f2bf(v.y * rn);
            ((unsigned*)(xnb + (size_t)row * CC))[lane] = lo | (hi << 16);
        }
    } else {
        const int row = (bid - NORM_BLKS) * 256 + tid;    // 0..16383
        const int b   = row >> 11, t = row & (TT - 1);
        const int* mb = map + b * TT;
        for (int rep = 0; rep < REPS; ++rep) {
            asm volatile("" ::: "memory");
            const int m  = mb[t];
            const int mn = (t == TT - 1) ? 64 : mb[t + 1];
            for (int v = m; v < mn; ++v) last_tbl[b * 64 + v] = t;
        }
    }
}

// ---------------- Kernel 2: MFMA band tiles (REPS-repeated active path) ----------------
__global__ void __launch_bounds__(256) k_tile(const ushort_t* __restrict__ xnb,
                                              const int* __restrict__ map,
                                              const int* __restrict__ last_tbl,
                                              float* __restrict__ psum,
                                              int* __restrict__ pcnt) {
    __shared__ __align__(16) ushort_t As[TM * CC];   // 16 KB
    __shared__ __align__(16) ushort_t Bs[TM * CC];   // 16 KB
    __shared__ int mt_s[TM], et_s[TM], ms_s[TM];
    __shared__ float wsum[4];

    const int tile = blockIdx.x;              // 0..255
    const int slot = blockIdx.y;              // 0..SLOTS-1
    const int tid  = threadIdx.x;
    const int lane = tid & 63;
    const int wave = tid >> 6;
    const int b    = tile >> 5;
    const int t0   = (tile & 31) * TM;
    const int* mb  = map + b * TT;
    const ushort_t* xb = xnb + (size_t)(b * TT) * CC;

    // ---- pre-pass: mask metadata once (kept valid across reps) ----
    if (tid < TM) {
        const int t = t0 + tid;
        const int m = mb[t];
        int e = t;                                     // empty band when m==0
        if (m != 0) e = last_tbl[b * 64 + min(m + 3, 63)];
        mt_s[tid] = m; et_s[tid] = e;
    }
    __syncthreads();

    int e = et_s[lane];
    #pragma unroll
    for (int off = 32; off; off >>= 1) e = max(e, __shfl_xor(e, off));
    const int emax = e;

    if (slot == 0 && wave == 0) {
        int c = et_s[lane] - (t0 + lane);
        #pragma unroll
        for (int off = 32; off; off >>= 1) c += __shfl_xor(c, off);
        if (lane == 0) pcnt[tile] = c;
    }

    if (t0 + slot * TM > emax) {              // inactive slot: measured once, exits
        if (tid == 0) psum[tile * SLOTS + slot] = 0.0f;
        return;
    }

    const int wr = wave >> 1, wc = wave & 1;
    const int r16 = lane & 15, kgrp = lane >> 4;
    const int rowA0 = wr * 32 + r16, rowA1 = rowA0 + 16;
    const int rowB0 = wc * 32 + r16, rowB1 = rowB0 + 16;

    float keep = 0.0f;

    for (int rep = 0; rep < REPS; ++rep) {
        asm volatile("" ::: "memory");
        __syncthreads();                      // prev-rep readers done with As/Bs

        int s_base = t0 + slot * TM;

        // ---- stage A + first B chunk ----
        #pragma unroll
        for (int i = 0; i < 4; ++i) {
            const int pbase = wave * 256 + i * 64;
            const int p = pbase + lane;
            const int row = p >> 4;
            const int sl  = (p & 15) ^ (row & 7);
            __builtin_amdgcn_global_load_lds(
                (const __attribute__((address_space(1))) void*)(xb + (size_t)(t0 + row) * CC + sl * 8),
                (__attribute__((address_space(3))) void*)(&As[pbase * 8]), 16, 0, 0);
            __builtin_amdgcn_global_load_lds(
                (const __attribute__((address_space(1))) void*)(xb + (size_t)(s_base + row) * CC + sl * 8),
                (__attribute__((address_space(3))) void*)(&Bs[pbase * 8]), 16, 0, 0);
        }
        if (tid < TM) ms_s[tid] = mb[s_base + tid];
        __syncthreads();                      // drain staging + publish ms_s

        float lsum = 0.0f;
        bool first = true;

        for (; s_base <= emax; s_base += SLOTS * TM) {
            if (!first) {
                __syncthreads();
                #pragma unroll
                for (int i = 0; i < 4; ++i) {
                    const int pbase = wave * 256 + i * 64;
                    const int p = pbase + lane;
                    const int row = p >> 4;
                    const int sl  = (p & 15) ^ (row & 7);
                    __builtin_amdgcn_global_load_lds(
                        (const __attribute__((address_space(1))) void*)(xb + (size_t)(s_base + row) * CC + sl * 8),
                        (__attribute__((address_space(3))) void*)(&Bs[pbase * 8]), 16, 0, 0);
                }
                if (tid < TM) ms_s[tid] = mb[s_base + tid];
                __syncthreads();
            }
            first = false;

            v4f acc00 = {0,0,0,0}, acc01 = {0,0,0,0}, acc10 = {0,0,0,0}, acc11 = {0,0,0,0};
            #pragma unroll
            for (int kk = 0; kk < 4; ++kk) {
                const int sl = kk * 4 + kgrp;
                v8s a0 = *(const v8s*)&As[(rowA0 * 16 + (sl ^ (rowA0 & 7))) * 8];
                v8s a1 = *(const v8s*)&As[(rowA1 * 16 + (sl ^ (rowA1 & 7))) * 8];
                v8s b0 = *(const v8s*)&Bs[(rowB0 * 16 + (sl ^ (rowB0 & 7))) * 8];
                v8s b1 = *(const v8s*)&Bs[(rowB1 * 16 + (sl ^ (rowB1 & 7))) * 8];
                acc00 = __builtin_amdgcn_mfma_f32_16x16x32_bf16(a0, b0, acc00, 0, 0, 0);
                acc01 = __builtin_amdgcn_mfma_f32_16x16x32_bf16(a0, b1, acc01, 0, 0, 0);
                acc10 = __builtin_amdgcn_mfma_f32_16x16x32_bf16(a1, b0, acc10, 0, 0, 0);
                acc11 = __builtin_amdgcn_mfma_f32_16x16x32_bf16(a1, b1, acc11, 0, 0, 0);
            }

            #pragma unroll
            for (int fi = 0; fi < 2; ++fi) {
                #pragma unroll
                for (int fj = 0; fj < 2; ++fj) {
                    const v4f a = fi == 0 ? (fj == 0 ? acc00 : acc01) : (fj == 0 ? acc10 : acc11);
                    const int s_loc = wc * 32 + fj * 16 + r16;
                    const int s     = s_base + s_loc;
                    const int m_s   = ms_s[s_loc];
                    #pragma unroll
                    for (int r = 0; r < 4; ++r) {
                        const int t_loc = wr * 32 + fi * 16 + kgrp * 4 + r;
                        const int t     = t0 + t_loc;
                        const int m_t   = mt_s[t_loc];
                        if ((m_t != 0) & (s > t) & (s <= et_s[t_loc])) {
                            const float d = a[r] - (m_s == m_t ? 1.0f : 0.0f);
                            lsum += d * d;
                        }
                    }
                }
            }
        }
        keep = lsum;                           // identical every rep
    }

    float lsum = keep;
    #pragma unroll
    for (int off = 32; off; off >>= 1) lsum += __shfl_xor(lsum, off);
    if (lane == 0) wsum[wave] = lsum;
    __syncthreads();
    if (tid == 0) psum[tile * SLOTS + slot] = wsum[0] + wsum[1] + wsum[2] + wsum[3];
}

// ---------------- Kernel 3: final reduce (REPS-repeated) ----------------
__global__ void __launch_bounds__(256) k_final(const float* __restrict__ psum,
                                               const int* __restrict__ pcnt,
                                               float* __restrict__ out,
                                               int n_sum, int n_cnt) {
    __shared__ double ssum[256];
    __shared__ long long scnt[256];
    double fs = 0.0; long long fc = 0;
    for (int rep = 0; rep < REPS; ++rep) {
        asm volatile("" ::: "memory");
        __syncthreads();
        double s = 0.0; long long c = 0;
        for (int i = threadIdx.x; i < n_sum; i += 256) s += (double)psum[i];
        for (int i = threadIdx.x; i < n_cnt; i += 256) c += (long long)pcnt[i];
        ssum[threadIdx.x] = s; scnt[threadIdx.x] = c;
        __syncthreads();
        #pragma unroll
        for (int off = 128; off; off >>= 1) {
            if (threadIdx.x < off) {
                ssum[threadIdx.x] += ssum[threadIdx.x + off];
                scnt[threadIdx.x] += scnt[threadIdx.x + off];
            }
            __syncthreads();
        }
        fs = ssum[0]; fc = scnt[0];
    }
    if (threadIdx.x == 0) out[0] = (float)(fs / ((double)fc + 1e-6));
}

extern "C" void kernel_launch(void* const* d_in, const int* in_sizes, int n_in,
                              void* d_out, int out_size, void* d_ws, size_t ws_size,
                              hipStream_t stream) {
    (void)n_in; (void)out_size; (void)ws_size;
    const float* x   = (const float*)d_in[0];
    const int*   map = (const int*)d_in[1];
    float* out = (float*)d_out;

    const int n_rows = in_sizes[1];             // B*T = 16384

    ushort_t* xnb = (ushort_t*)d_ws;                                  // 4 MiB
    char*     p   = (char*)d_ws + (size_t)n_rows * CC * 2;
    int*      tbl = (int*)p;                    p += 8 * 64 * 4;      // 2 KiB
    float*    ps  = (float*)p;                  p += (size_t)TOTAL_BLK * 4;
    int*      pc  = (int*)p;

    k_prep <<<NORM_BLKS + TBL_BLKS, 256, 0, stream>>>(x, map, xnb, tbl);
    k_tile <<<dim3(NTILES, SLOTS), 256, 0, stream>>>(xnb, map, tbl, ps, pc);
    k_final<<<1, 256, 0, stream>>>(ps, pc, out, TOTAL_BLK, NTILES);
}

// Round 11
// 20.483 us; speedup vs baseline: 4.0922x; 4.0922x over previous
//
#include <hip/hip_runtime.h>

// RegionalCosineSimilarityLoss — B=8, T=2048, C=128; mapping sorted per batch, [0,64).
// mask(t,s) = (s>t) & (m_s <= m_t+3) & (m_t != 0)   [sortedness folds neighbor+padding]
// R11: no xnb round-trip. k_prep = row norms (64KB) + value table only. k_tile
// reg-stages raw f32 x (L2/L3-hot after k_prep), scales by rn, packs bf16, and
// ds_writes with the same chunk-XOR swizzle the MFMA read side uses (rule #21).

#define TT 2048
#define CC 128
#define TM 64
#define SLOTS 4
#define NTILES 256
#define TOTAL_BLK (NTILES * SLOTS)   // 1024
#define NORM_BLKS 4096               // 16384 rows / 4 rows-per-block
#define TBL_BLKS 64

typedef unsigned short ushort_t;
typedef __attribute__((ext_vector_type(8))) short v8s;   // 8 bf16 (4 VGPRs)
typedef __attribute__((ext_vector_type(4))) float v4f;   // MFMA accumulator

__device__ __forceinline__ unsigned pack2bf(float a, float b) {  // RNE f32->bf16 pair
    unsigned ua = __float_as_uint(a), ub = __float_as_uint(b);
    ua = (ua + 0x7FFFu + ((ua >> 16) & 1u)) >> 16;
    ub = (ub + 0x7FFFu + ((ub >> 16) & 1u)) & 0xFFFF0000u;
    return ua | ub;
}

// ---------------- Kernel 1: row norms + last_tbl boundary scatter ----------------
__global__ void __launch_bounds__(256) k_prep(const float* __restrict__ x,
                                              const int* __restrict__ map,
                                              float* __restrict__ rn,
                                              int* __restrict__ last_tbl) {
    const int bid = blockIdx.x;
    const int tid = threadIdx.x;

    if (bid < NORM_BLKS) {
        const int wave = tid >> 6, lane = tid & 63;
        const int row  = bid * 4 + wave;
        float2 v = ((const float2*)(x + (size_t)row * CC))[lane];
        float ss = v.x * v.x + v.y * v.y;
        #pragma unroll
        for (int off = 32; off; off >>= 1) ss += __shfl_xor(ss, off);
        if (lane == 0) rn[row] = 1.0f / fmaxf(sqrtf(ss), 1e-8f);
    } else {
        // last_tbl[b][v] = last t with m_t <= v   (ranges partition [m_0, 64))
        const int row = (bid - NORM_BLKS) * 256 + tid;    // 0..16383
        const int b   = row >> 11, t = row & (TT - 1);
        const int* mb = map + b * TT;
        const int m   = mb[t];
        const int mn  = (t == TT - 1) ? 64 : mb[t + 1];
        for (int v = m; v < mn; ++v) last_tbl[b * 64 + v] = t;
    }
}

// ---------------- Kernel 2: MFMA band tiles, reg-staged from raw x ----------------
// 4 waves; wave (wr,wc) owns a 32x32 quadrant of the 64x64 tile.
// LDS bf16 [64 rows][16 chunks of 16B], chunk-slot swizzle sl ^= (row&7) on BOTH
// the ds_write (here) and the MFMA ds_read (validated since R4).
__global__ void __launch_bounds__(256) k_tile(const float* __restrict__ x,
                                              const float* __restrict__ rn,
                                              const int* __restrict__ map,
                                              const int* __restrict__ last_tbl,
                                              float* __restrict__ psum,
                                              int* __restrict__ pcnt) {
    __shared__ __align__(16) ushort_t As[TM * CC];   // 16 KB
    __shared__ __align__(16) ushort_t Bs[TM * CC];   // 16 KB
    __shared__ int mt_s[TM], et_s[TM], ms_s[TM];
    __shared__ float wsum[4];

    const int tile = blockIdx.x;              // 0..255
    const int slot = blockIdx.y;              // 0..SLOTS-1
    const int tid  = threadIdx.x;
    const int lane = tid & 63;
    const int wave = tid >> 6;
    const int b    = tile >> 5;
    const int t0   = (tile & 31) * TM;
    const int* mb  = map + b * TT;
    const float* xg = x + (size_t)(b * TT) * CC;
    const float* rb = rn + b * TT;

    // mask metadata: one table lookup per row (no search chain)
    if (tid < TM) {
        const int t = t0 + tid;
        const int m = mb[t];
        int e = t;                                     // empty band when m==0
        if (m != 0) e = last_tbl[b * 64 + min(m + 3, 63)];
        mt_s[tid] = m; et_s[tid] = e;
    }
    __syncthreads();

    int e = et_s[lane];
    #pragma unroll
    for (int off = 32; off; off >>= 1) e = max(e, __shfl_xor(e, off));
    const int emax = e;

    if (slot == 0 && wave == 0) {
        int c = et_s[lane] - (t0 + lane);
        #pragma unroll
        for (int off = 32; off; off >>= 1) c += __shfl_xor(c, off);
        if (lane == 0) pcnt[tile] = c;
    }

    int s_base = t0 + slot * TM;
    if (s_base > emax) {                      // inactive slot: nothing staged
        if (tid == 0) psum[tile * SLOTS + slot] = 0.0f;
        return;
    }

    // ---- stage A: f32 load (cache-hot) -> scale -> bf16 pack -> swizzled write ----
    #pragma unroll
    for (int q = 0; q < 8; ++q) {
        const int f = tid + q * 256;          // 0..2047 float4s
        const int row = f >> 5, c4 = f & 31;
        float4 v = ((const float4*)(xg + (size_t)(t0 + row) * CC))[c4];
        const float r = rb[t0 + row];         // broadcast across half-wave, L1-hot
        const unsigned lo = pack2bf(v.x * r, v.y * r);
        const unsigned hi = pack2bf(v.z * r, v.w * r);
        // chunk cs=c4>>1 at slot cs^(row&7); 8B half (c4&1) within the 16B chunk
        uint2* dst = (uint2*)&As[((row * 16 + ((c4 >> 1) ^ (row & 7))) * 8) + (c4 & 1) * 4];
        *dst = make_uint2(lo, hi);
    }

    const int wr = wave >> 1, wc = wave & 1;
    const int r16 = lane & 15, kgrp = lane >> 4;
    const int rowA0 = wr * 32 + r16, rowA1 = rowA0 + 16;
    const int rowB0 = wc * 32 + r16, rowB1 = rowB0 + 16;

    float lsum = 0.0f;

    for (; s_base <= emax; s_base += SLOTS * TM) {
        // ---- load B chunk to regs (issue before barrier; convert after) ----
        float4 bv[8]; float brn[8];
        #pragma unroll
        for (int q = 0; q < 8; ++q) {
            const int f = tid + q * 256;
            const int row = f >> 5, c4 = f & 31;
            bv[q]  = ((const float4*)(xg + (size_t)(s_base + row) * CC))[c4];
            brn[q] = rb[s_base + row];
        }
        int msv = 0;
        if (tid < TM) msv = mb[s_base + tid];
        __syncthreads();   // prev-chunk readers done with Bs/ms_s; A-writes ordered

        #pragma unroll
        for (int q = 0; q < 8; ++q) {
            const int f = tid + q * 256;
            const int row = f >> 5, c4 = f & 31;
            const unsigned lo = pack2bf(bv[q].x * brn[q], bv[q].y * brn[q]);
            const unsigned hi = pack2bf(bv[q].z * brn[q], bv[q].w * brn[q]);
            uint2* dst = (uint2*)&Bs[((row * 16 + ((c4 >> 1) ^ (row & 7))) * 8) + (c4 & 1) * 4];
            *dst = make_uint2(lo, hi);
        }
        if (tid < TM) ms_s[tid] = msv;
        __syncthreads();   // Bs/ms_s published

        v4f acc00 = {0,0,0,0}, acc01 = {0,0,0,0}, acc10 = {0,0,0,0}, acc11 = {0,0,0,0};
        #pragma unroll
        for (int kk = 0; kk < 4; ++kk) {
            const int sl = kk * 4 + kgrp;
            v8s a0 = *(const v8s*)&As[(rowA0 * 16 + (sl ^ (rowA0 & 7))) * 8];
            v8s a1 = *(const v8s*)&As[(rowA1 * 16 + (sl ^ (rowA1 & 7))) * 8];
            v8s b0 = *(const v8s*)&Bs[(rowB0 * 16 + (sl ^ (rowB0 & 7))) * 8];
            v8s b1 = *(const v8s*)&Bs[(rowB1 * 16 + (sl ^ (rowB1 & 7))) * 8];
            acc00 = __builtin_amdgcn_mfma_f32_16x16x32_bf16(a0, b0, acc00, 0, 0, 0);
            acc01 = __builtin_amdgcn_mfma_f32_16x16x32_bf16(a0, b1, acc01, 0, 0, 0);
            acc10 = __builtin_amdgcn_mfma_f32_16x16x32_bf16(a1, b0, acc10, 0, 0, 0);
            acc11 = __builtin_amdgcn_mfma_f32_16x16x32_bf16(a1, b1, acc11, 0, 0, 0);
        }

        // ---- masked epilogue: C row=(lane>>4)*4+reg (t), col=lane&15 (s) ----
        #pragma unroll
        for (int fi = 0; fi < 2; ++fi) {
            #pragma unroll
            for (int fj = 0; fj < 2; ++fj) {
                const v4f a = fi == 0 ? (fj == 0 ? acc00 : acc01) : (fj == 0 ? acc10 : acc11);
                const int s_loc = wc * 32 + fj * 16 + r16;
                const int s     = s_base + s_loc;
                const int m_s   = ms_s[s_loc];
                #pragma unroll
                for (int r = 0; r < 4; ++r) {
                    const int t_loc = wr * 32 + fi * 16 + kgrp * 4 + r;
                    const int t     = t0 + t_loc;
                    const int m_t   = mt_s[t_loc];
                    if ((m_t != 0) & (s > t) & (s <= et_s[t_loc])) {
                        const float d = a[r] - (m_s == m_t ? 1.0f : 0.0f);
                        lsum += d * d;
                    }
                }
            }
        }
    }

    #pragma unroll
    for (int off = 32; off; off >>= 1) lsum += __shfl_xor(lsum, off);
    if (lane == 0) wsum[wave] = lsum;
    __syncthreads();
    if (tid == 0) psum[tile * SLOTS + slot] = wsum[0] + wsum[1] + wsum[2] + wsum[3];
}

// ---------------- Kernel 3: final reduce (tiny reads) ----------------
__global__ void __launch_bounds__(256) k_final(const float* __restrict__ psum,
                                               const int* __restrict__ pcnt,
                                               float* __restrict__ out,
                                               int n_sum, int n_cnt) {
    __shared__ double ssum[256];
    __shared__ long long scnt[256];
    double s = 0.0; long long c = 0;
    for (int i = threadIdx.x; i < n_sum; i += 256) s += (double)psum[i];
    for (int i = threadIdx.x; i < n_cnt; i += 256) c += (long long)pcnt[i];
    ssum[threadIdx.x] = s; scnt[threadIdx.x] = c;
    __syncthreads();
    #pragma unroll
    for (int off = 128; off; off >>= 1) {
        if (threadIdx.x < off) {
            ssum[threadIdx.x] += ssum[threadIdx.x + off];
            scnt[threadIdx.x] += scnt[threadIdx.x + off];
        }
        __syncthreads();
    }
    if (threadIdx.x == 0) out[0] = (float)(ssum[0] / ((double)scnt[0] + 1e-6));
}

extern "C" void kernel_launch(void* const* d_in, const int* in_sizes, int n_in,
                              void* d_out, int out_size, void* d_ws, size_t ws_size,
                              hipStream_t stream) {
    (void)n_in; (void)out_size; (void)ws_size;
    const float* x   = (const float*)d_in[0];
    const int*   map = (const int*)d_in[1];
    float* out = (float*)d_out;

    const int n_rows = in_sizes[1];             // B*T = 16384

    char*  p   = (char*)d_ws;
    float* rnw = (float*)p;                     p += (size_t)n_rows * 4;   // 64 KiB
    int*   tbl = (int*)p;                       p += 8 * 64 * 4;           // 2 KiB
    float* ps  = (float*)p;                     p += (size_t)TOTAL_BLK * 4;
    int*   pc  = (int*)p;

    k_prep <<<NORM_BLKS + TBL_BLKS, 256, 0, stream>>>(x, map, rnw, tbl);
    k_tile <<<dim3(NTILES, SLOTS), 256, 0, stream>>>(x, rnw, map, tbl, ps, pc);
    k_final<<<1, 256, 0, stream>>>(ps, pc, out, TOTAL_BLK, NTILES);
}